// Round 1
// baseline (321.800 us; speedup 1.0000x reference)
//
#include <hip/hip_runtime.h>
#include <math.h>

// Problem constants (from reference setup_inputs): B=8, C=24, H=320, W=640
#define BB 8
#define CC 24
#define HH 320
#define WW 640
#define HWC (HH * WW)          // 204800 pixels per (b, c) plane
#define NPIX (BB * HWC)        // 1,638,400 output pixels
#define NP4 (NPIX / 4)         // 409,600 float4 groups

__global__ __launch_bounds__(256) void sparse_regression_kernel(
    const float* __restrict__ cost,
    const float* __restrict__ disp,
    float* __restrict__ pred,      // [B, H, W]
    float* __restrict__ prob)      // [B, 2, H, W]
{
    long long g = (long long)blockIdx.x * blockDim.x + threadIdx.x;
    if (g >= NP4) return;
    long long p = g * 4;                   // first pixel of this group
    int b = (int)(p / HWC);                // HWC % 4 == 0 -> group never straddles b
    long long hw = p - (long long)b * HWC;

    const float* cbase = cost + (long long)b * CC * HWC + hw;
    const float* dbase = disp + (long long)b * CC * HWC + hw;

    float c1[4], c2[4], d1[4], d2[4];
    #pragma unroll
    for (int j = 0; j < 4; ++j) {
        c1[j] = -INFINITY; c2[j] = -INFINITY;
        d1[j] = 0.0f;      d2[j] = 0.0f;
    }

    // Streaming top-2 over C. Strict '>' keeps the earlier (lower) index on
    // ties, matching jax.lax.top_k semantics.
    #pragma unroll
    for (int c = 0; c < CC; ++c) {
        float4 cv = *reinterpret_cast<const float4*>(cbase + (long long)c * HWC);
        float4 dv = *reinterpret_cast<const float4*>(dbase + (long long)c * HWC);
        float ccv[4] = {cv.x, cv.y, cv.z, cv.w};
        float ddv[4] = {dv.x, dv.y, dv.z, dv.w};
        #pragma unroll
        for (int j = 0; j < 4; ++j) {
            bool gt1 = ccv[j] > c1[j];
            bool gt2 = ccv[j] > c2[j];
            float nc2 = gt1 ? c1[j] : (gt2 ? ccv[j] : c2[j]);
            float nd2 = gt1 ? d1[j] : (gt2 ? ddv[j] : d2[j]);
            c1[j] = gt1 ? ccv[j] : c1[j];
            d1[j] = gt1 ? ddv[j] : d1[j];
            c2[j] = nc2;
            d2[j] = nd2;
        }
    }

    // softmax over [c1, c2] with c1 >= c2:
    //   p1 = 1 / (1 + e^(c2-c1)),  p2 = 1 - p1
    float pr[4], p1a[4], p2a[4];
    #pragma unroll
    for (int j = 0; j < 4; ++j) {
        float e = __expf(c2[j] - c1[j]);     // in (0, 1]
        float inv = 1.0f / (1.0f + e);
        float p1 = inv;
        float p2 = e * inv;
        p1a[j] = p1;
        p2a[j] = p2;
        pr[j]  = d1[j] * p1 + d2[j] * p2;
    }

    // Writes: pred at [b, hw]; prob at [b, 0, hw] and [b, 1, hw]
    float4* predv = reinterpret_cast<float4*>(pred + p);
    *predv = make_float4(pr[0], pr[1], pr[2], pr[3]);

    float* prob_b = prob + (long long)b * 2 * HWC + hw;
    *reinterpret_cast<float4*>(prob_b)       = make_float4(p1a[0], p1a[1], p1a[2], p1a[3]);
    *reinterpret_cast<float4*>(prob_b + HWC) = make_float4(p2a[0], p2a[1], p2a[2], p2a[3]);
}

extern "C" void kernel_launch(void* const* d_in, const int* in_sizes, int n_in,
                              void* d_out, int out_size, void* d_ws, size_t ws_size,
                              hipStream_t stream) {
    const float* cost = (const float*)d_in[0];
    const float* disp = (const float*)d_in[1];
    float* pred = (float*)d_out;                 // first B*H*W floats
    float* prob = (float*)d_out + NPIX;          // next B*2*H*W floats

    const int threads = 256;
    const int blocks = (NP4 + threads - 1) / threads;   // 1600
    sparse_regression_kernel<<<blocks, threads, 0, stream>>>(cost, disp, pred, prob);
}

// Round 2
// 316.425 us; speedup vs baseline: 1.0170x; 1.0170x over previous
//
#include <hip/hip_runtime.h>
#include <math.h>

// Problem constants (from reference setup_inputs): B=8, C=24, H=320, W=640
#define BB 8
#define CC 24
#define HH 320
#define WW 640
#define HWC (HH * WW)          // 204800 pixels per (b, c) plane
#define NPIX (BB * HWC)        // 1,638,400 output pixels
#define NP2 (NPIX / 2)         // 819,200 float2 groups
#define CB 8                   // channel batch: 16 loads in flight per thread

__global__ __launch_bounds__(256) void sparse_regression_kernel(
    const float* __restrict__ cost,
    const float* __restrict__ disp,
    float* __restrict__ pred,      // [B, H, W]
    float* __restrict__ prob)      // [B, 2, H, W]
{
    long long g = (long long)blockIdx.x * blockDim.x + threadIdx.x;
    if (g >= NP2) return;
    long long p = g * 2;                   // first pixel of this pair
    int b = (int)(p / HWC);                // HWC % 2 == 0 -> pair never straddles b
    long long hw = p - (long long)b * HWC;

    const float* cbase = cost + (long long)b * CC * HWC + hw;
    const float* dbase = disp + (long long)b * CC * HWC + hw;

    float c1[2], c2[2], d1[2], d2[2];
    #pragma unroll
    for (int j = 0; j < 2; ++j) {
        c1[j] = -INFINITY; c2[j] = -INFINITY;
        d1[j] = 0.0f;      d2[j] = 0.0f;
    }

    // Streaming top-2 over C, in batches of CB channels so the compiler can
    // issue 2*CB loads back-to-back (ILP) before consuming any of them.
    // Strict '>' keeps the earlier (lower) index on ties == jax.lax.top_k.
    #pragma unroll
    for (int cb = 0; cb < CC; cb += CB) {
        float2 cv[CB], dv[CB];
        #pragma unroll
        for (int k = 0; k < CB; ++k) {
            cv[k] = *reinterpret_cast<const float2*>(cbase + (long long)(cb + k) * HWC);
            dv[k] = *reinterpret_cast<const float2*>(dbase + (long long)(cb + k) * HWC);
        }
        #pragma unroll
        for (int k = 0; k < CB; ++k) {
            float ccv[2] = {cv[k].x, cv[k].y};
            float ddv[2] = {dv[k].x, dv[k].y};
            #pragma unroll
            for (int j = 0; j < 2; ++j) {
                bool gt1 = ccv[j] > c1[j];
                bool gt2 = ccv[j] > c2[j];
                float nc2 = gt1 ? c1[j] : (gt2 ? ccv[j] : c2[j]);
                float nd2 = gt1 ? d1[j] : (gt2 ? ddv[j] : d2[j]);
                c1[j] = gt1 ? ccv[j] : c1[j];
                d1[j] = gt1 ? ddv[j] : d1[j];
                c2[j] = nc2;
                d2[j] = nd2;
            }
        }
    }

    // softmax over [c1, c2] with c1 >= c2:
    //   p1 = 1 / (1 + e^(c2-c1)),  p2 = e * p1
    float pr[2], p1a[2], p2a[2];
    #pragma unroll
    for (int j = 0; j < 2; ++j) {
        float e = __expf(c2[j] - c1[j]);     // in (0, 1]
        float inv = 1.0f / (1.0f + e);
        p1a[j] = inv;
        p2a[j] = e * inv;
        pr[j]  = d1[j] * p1a[j] + d2[j] * p2a[j];
    }

    // Writes: pred at [b, hw]; prob at [b, 0, hw] and [b, 1, hw]
    *reinterpret_cast<float2*>(pred + p) = make_float2(pr[0], pr[1]);

    float* prob_b = prob + (long long)b * 2 * HWC + hw;
    *reinterpret_cast<float2*>(prob_b)       = make_float2(p1a[0], p1a[1]);
    *reinterpret_cast<float2*>(prob_b + HWC) = make_float2(p2a[0], p2a[1]);
}

extern "C" void kernel_launch(void* const* d_in, const int* in_sizes, int n_in,
                              void* d_out, int out_size, void* d_ws, size_t ws_size,
                              hipStream_t stream) {
    const float* cost = (const float*)d_in[0];
    const float* disp = (const float*)d_in[1];
    float* pred = (float*)d_out;                 // first B*H*W floats
    float* prob = (float*)d_out + NPIX;          // next B*2*H*W floats

    const int threads = 256;
    const int blocks = (NP2 + threads - 1) / threads;   // 3200
    sparse_regression_kernel<<<blocks, threads, 0, stream>>>(cost, disp, pred, prob);
}